// Round 1
// baseline (3302.993 us; speedup 1.0000x reference)
//
#include <hip/hip_runtime.h>
#include <hip/hip_bf16.h>
#include <stdint.h>

#define BB 16
#define TT 256
#define HH 256
#define EE 256
#define GG 1024      // 4*H
#define VV 50257
#define VP 50304     // padded to multiple of 128
#define NN 4096      // B*T

typedef unsigned short u16;
typedef __attribute__((ext_vector_type(8))) short short8;
typedef __attribute__((ext_vector_type(4))) float f32x4;

__device__ __forceinline__ float sigm(float x){
    float e = __builtin_amdgcn_exp2f(fminf(-x*1.44269504f, 60.0f));
    return 1.0f/(1.0f+e);
}
__device__ __forceinline__ float tanha(float x){
    float e = __builtin_amdgcn_exp2f(fminf(x*2.885390082f, 60.0f));
    return (e-1.0f)/(e+1.0f);
}
__device__ __forceinline__ u16 f2bf(float f){
    uint32_t u = __float_as_uint(f);
    u = (u + 0x7FFFu + ((u>>16)&1u)) >> 16;
    return (u16)u;
}

// ---------------- Wout cast + transpose:  Wout[256][50257] f32 -> WoutT[50304][256] bf16
__global__ __launch_bounds__(256) void cast_transpose_wout(const float* __restrict__ Wout,
                                                           u16* __restrict__ WoutT){
    __shared__ u16 tile[64][65];
    int n0 = blockIdx.x * 64;
    int k0 = blockIdx.y * 64;
    int tid = threadIdx.x;
    int r  = tid >> 2;   // 0..63
    int cq = tid & 3;    // 0..3
    #pragma unroll
    for (int i = 0; i < 16; ++i){
        int n = n0 + cq*16 + i;
        float v = (n < VV) ? Wout[(size_t)(k0 + r)*VV + n] : 0.0f;
        tile[cq*16 + i][r] = f2bf(v);
    }
    __syncthreads();
    #pragma unroll
    for (int i4 = 0; i4 < 4; ++i4){
        int kl = cq*16 + i4*4;
        uint2 v;
        v.x = (uint32_t)tile[r][kl+0] | ((uint32_t)tile[r][kl+1] << 16);
        v.y = (uint32_t)tile[r][kl+2] | ((uint32_t)tile[r][kl+3] << 16);
        *(uint2*)(&WoutT[(size_t)(n0 + r)*256 + k0 + kl]) = v;
    }
}

// ---------------- G1[n][g] = b1[g] + sum_e emb[tok[n]][e] * W1[e][g]
__global__ __launch_bounds__(256) void g1_kernel(const int* __restrict__ tok, const float* __restrict__ emb,
                                                 const float* __restrict__ W1, const float* __restrict__ b1,
                                                 float* __restrict__ G1){
    __shared__ float xs[64*64];   // X^T[k][n]
    __shared__ float wsm[64*64];  // W[k][g]
    int n0 = blockIdx.x * 64;
    int g0 = blockIdx.y * 64;
    int tid = threadIdx.x;
    int sl = tid & 63;
    int kk = (tid >> 6) * 16;
    int mytok = tok[n0 + sl];
    float acc[4][4] = {};
    int ni = tid & 15, gi = tid >> 4;
    for (int kc = 0; kc < 4; ++kc){
        int k0 = kc*64;
        __syncthreads();
        #pragma unroll
        for (int i4 = 0; i4 < 4; ++i4){
            float4 xv = *(const float4*)(&emb[(size_t)mytok*EE + k0 + kk + i4*4]);
            xs[(kk+i4*4+0)*64 + sl] = xv.x;
            xs[(kk+i4*4+1)*64 + sl] = xv.y;
            xs[(kk+i4*4+2)*64 + sl] = xv.z;
            xs[(kk+i4*4+3)*64 + sl] = xv.w;
        }
        #pragma unroll
        for (int i = 0; i < 16; ++i){
            wsm[(kk+i)*64 + sl] = W1[(size_t)(k0+kk+i)*GG + g0 + sl];
        }
        __syncthreads();
        for (int k = 0; k < 64; ++k){
            float4 av = *(const float4*)(&xs[k*64 + ni*4]);
            float4 bv = *(const float4*)(&wsm[k*64 + gi*4]);
            float a_[4] = {av.x, av.y, av.z, av.w};
            float b_[4] = {bv.x, bv.y, bv.z, bv.w};
            #pragma unroll
            for (int i = 0; i < 4; ++i)
                #pragma unroll
                for (int j = 0; j < 4; ++j)
                    acc[i][j] += a_[i]*b_[j];
        }
    }
    #pragma unroll
    for (int i = 0; i < 4; ++i){
        int row = n0 + ni*4 + i;
        float4 o;
        o.x = acc[i][0] + b1[g0+gi*4+0];
        o.y = acc[i][1] + b1[g0+gi*4+1];
        o.z = acc[i][2] + b1[g0+gi*4+2];
        o.w = acc[i][3] + b1[g0+gi*4+3];
        *(float4*)(&G1[(size_t)row*GG + g0 + gi*4]) = o;
    }
}

// ---------------- One pipeline stage: blocks 0..31 do L1 step t, blocks 32..95 do L2 step t-1
__global__ __launch_bounds__(256) void step_kernel(int t,
        const float* __restrict__ G1, const float* __restrict__ W1,
        const float* __restrict__ W2, const float* __restrict__ b2,
        float* __restrict__ h1_all, float* __restrict__ h2_all,
        float* __restrict__ c1s, float* __restrict__ c2s,
        u16* __restrict__ h2b){
    __shared__ float smem[8192 + 2048 + 512];
    float* ubuf = smem;           // staged h (L1: 16x256, L2: 16x512)
    float* red  = smem + 8192;    // reduction scratch
    float* gmat = smem + 8192 + 2048;
    int bid = blockIdx.x;
    int tid = threadIdx.x;
    if (bid < 32){
        // ================= L1: gates = G1[t] + h1_{t-1} @ W1[256:512]
        if (t >= TT) return;
        int w  = bid;         // owns hidden cols w*8 .. w*8+7
        int rc = tid >> 4;    // 0..15  row-chunk (16 rows each)
        int cg = tid & 15;    // 0..15  col-group (2 gate-cols)
        int cb  = tid >> 4;   // combine role: batch
        int ccg = tid & 15;
        float g1v[2];
        #pragma unroll
        for (int j = 0; j < 2; ++j){
            int gl = ccg*2 + j;
            int gc = (gl>>3)*HH + w*8 + (gl&7);
            g1v[j] = G1[((size_t)cb*TT + t)*GG + gc];
        }
        float wreg[2][16];
        #pragma unroll
        for (int j = 0; j < 2; ++j){
            int gl = cg*2 + j;
            int gc = (gl>>3)*HH + w*8 + (gl&7);
            #pragma unroll
            for (int i = 0; i < 16; ++i)
                wreg[j][i] = W1[(size_t)(HH + rc*16 + i)*GG + gc];
        }
        if (t > 0){
            const float4* src = (const float4*)(h1_all + (size_t)(t-1)*(BB*HH));
            float4* dst = (float4*)ubuf;
            #pragma unroll
            for (int j = 0; j < 4; ++j) dst[j*256 + tid] = src[j*256 + tid];
        }
        __syncthreads();
        float pp[2][16] = {};
        if (t > 0){
            #pragma unroll
            for (int b = 0; b < 16; ++b){
                const float4* hp4 = (const float4*)(ubuf + b*256 + rc*16);
                float4 h0 = hp4[0], h1v = hp4[1], h2v = hp4[2], h3v = hp4[3];
                float hv[16] = {h0.x,h0.y,h0.z,h0.w, h1v.x,h1v.y,h1v.z,h1v.w,
                                h2v.x,h2v.y,h2v.z,h2v.w, h3v.x,h3v.y,h3v.z,h3v.w};
                #pragma unroll
                for (int i = 0; i < 16; ++i){
                    pp[0][b] += hv[i]*wreg[0][i];
                    pp[1][b] += hv[i]*wreg[1][i];
                }
            }
        }
        #pragma unroll
        for (int m = 16; m <= 32; m <<= 1){
            #pragma unroll
            for (int j = 0; j < 2; ++j)
                #pragma unroll
                for (int b = 0; b < 16; ++b)
                    pp[j][b] += __shfl_xor(pp[j][b], m, 64);
        }
        int wave = tid >> 6;
        if ((tid & 0x30) == 0){
            #pragma unroll
            for (int j = 0; j < 2; ++j)
                #pragma unroll
                for (int b = 0; b < 16; ++b)
                    red[((wave*16 + cg)*2 + j)*16 + b] = pp[j][b];
        }
        __syncthreads();
        #pragma unroll
        for (int j = 0; j < 2; ++j){
            float s = g1v[j];
            #pragma unroll
            for (int wv = 0; wv < 4; ++wv) s += red[((wv*16 + ccg)*2 + j)*16 + cb];
            gmat[cb*32 + ccg*2 + j] = s;
        }
        __syncthreads();
        if (tid < 128){
            int b = tid >> 3, cl = tid & 7;
            float gi_ = gmat[b*32 + cl];
            float gj_ = gmat[b*32 + 8  + cl];
            float gf_ = gmat[b*32 + 16 + cl];
            float go_ = gmat[b*32 + 24 + cl];
            int c = w*8 + cl;
            int idx = b*HH + c;
            float cold = c1s[idx];
            float cn = cold * sigm(gf_ + 1.0f) + sigm(gi_) * tanha(gj_);
            float hn = tanha(cn) * sigm(go_);
            c1s[idx] = cn;
            h1_all[(size_t)t*(BB*HH) + idx] = hn;
        }
    } else {
        // ================= L2: gates = b2 + [h1_t ; h2_{t-1}] @ W2
        if (t < 1) return;
        int tt = t - 1;
        int w2 = bid - 32;    // owns hidden cols w2*4 .. w2*4+3
        int rc = tid >> 3;    // 0..31 (16 rows each over 512)
        int cg = tid & 7;     // 0..7  (2 gate-cols)
        int cb  = tid >> 4;   // 0..15 combine batch
        int cgl = tid & 15;   // gl 0..15
        float b2v = b2[(cgl>>2)*HH + w2*4 + (cgl&3)];
        float wreg[2][16];
        #pragma unroll
        for (int j = 0; j < 2; ++j){
            int gl = cg*2 + j;
            int gc = (gl>>2)*HH + w2*4 + (gl&3);
            #pragma unroll
            for (int i = 0; i < 16; ++i)
                wreg[j][i] = W2[(size_t)(rc*16 + i)*GG + gc];
        }
        {
            const float4* s1 = (const float4*)(h1_all + (size_t)tt*(BB*HH));
            float4* dst = (float4*)ubuf;
            #pragma unroll
            for (int j = 0; j < 4; ++j){
                int flat = j*256 + tid;
                int b = flat >> 6, r4 = flat & 63;
                dst[b*128 + r4] = s1[flat];
            }
            if (tt > 0){
                const float4* s2 = (const float4*)h2_all;
                #pragma unroll
                for (int j = 0; j < 4; ++j){
                    int flat = j*256 + tid;
                    int b = flat >> 6, r4 = flat & 63;
                    dst[b*128 + 64 + r4] = s2[((size_t)b*TT + (tt-1))*64 + r4];
                }
            } else {
                float4 z = {0.f,0.f,0.f,0.f};
                #pragma unroll
                for (int j = 0; j < 4; ++j){
                    int flat = j*256 + tid;
                    int b = flat >> 6, r4 = flat & 63;
                    dst[b*128 + 64 + r4] = z;
                }
            }
        }
        __syncthreads();
        float pp[2][16] = {};
        #pragma unroll
        for (int b = 0; b < 16; ++b){
            const float4* up4 = (const float4*)(ubuf + b*512 + rc*16);
            float4 u0 = up4[0], u1 = up4[1], u2 = up4[2], u3 = up4[3];
            float uv[16] = {u0.x,u0.y,u0.z,u0.w, u1.x,u1.y,u1.z,u1.w,
                            u2.x,u2.y,u2.z,u2.w, u3.x,u3.y,u3.z,u3.w};
            #pragma unroll
            for (int i = 0; i < 16; ++i){
                pp[0][b] += uv[i]*wreg[0][i];
                pp[1][b] += uv[i]*wreg[1][i];
            }
        }
        #pragma unroll
        for (int m = 8; m <= 32; m <<= 1){
            #pragma unroll
            for (int j = 0; j < 2; ++j)
                #pragma unroll
                for (int b = 0; b < 16; ++b)
                    pp[j][b] += __shfl_xor(pp[j][b], m, 64);
        }
        int wave = tid >> 6;
        if ((tid & 0x38) == 0){
            #pragma unroll
            for (int j = 0; j < 2; ++j)
                #pragma unroll
                for (int b = 0; b < 16; ++b)
                    red[((wave*8 + cg)*2 + j)*16 + b] = pp[j][b];
        }
        __syncthreads();
        {
            float s = b2v;
            #pragma unroll
            for (int wv = 0; wv < 4; ++wv) s += red[((wv*8 + (cgl>>1))*2 + (cgl&1))*16 + cb];
            gmat[cb*16 + cgl] = s;
        }
        __syncthreads();
        if (tid < 64){
            int b = tid >> 2, cl = tid & 3;
            float gi_ = gmat[b*16 + cl];
            float gj_ = gmat[b*16 + 4  + cl];
            float gf_ = gmat[b*16 + 8  + cl];
            float go_ = gmat[b*16 + 12 + cl];
            int c = w2*4 + cl;
            int idx = b*HH + c;
            float cold = c2s[idx];
            float cn = cold * sigm(gf_ + 1.0f) + sigm(gi_) * tanha(gj_);
            float hn = tanha(cn) * sigm(go_);
            c2s[idx] = cn;
            size_t oi = ((size_t)b*TT + tt)*HH + c;
            h2_all[oi] = hn;
            h2b[oi] = f2bf(hn);
        }
    }
}

// ---------------- out = h2b[4096,256] @ WoutT^T + bout   (bf16 MFMA, fp32 accumulate)
__global__ __launch_bounds__(256) void out_gemm(const u16* __restrict__ A, const u16* __restrict__ Bt,
                                                const float* __restrict__ bout, float* __restrict__ out){
    int bx = blockIdx.x;
    int mb = bx & 63;      // 64 m-tiles of 64
    int nb = bx >> 6;      // 393 n-tiles of 128
    int m0 = mb*64, n0 = nb*128;
    int tid = threadIdx.x;
    int wave = tid >> 6, lane = tid & 63;
    int lr = lane & 15, lh = lane >> 4;
    f32x4 acc[8];
    #pragma unroll
    for (int nf = 0; nf < 8; ++nf) acc[nf] = (f32x4){0.f,0.f,0.f,0.f};
    const short8* Ap = (const short8*)(A + (size_t)(m0 + wave*16 + lr)*256);
    #pragma unroll
    for (int ks = 0; ks < 8; ++ks){
        short8 av = Ap[ks*4 + lh];
        #pragma unroll
        for (int nf = 0; nf < 8; ++nf){
            const short8* Bp = (const short8*)(Bt + (size_t)(n0 + nf*16 + lr)*256);
            short8 bv = Bp[ks*4 + lh];
            acc[nf] = __builtin_amdgcn_mfma_f32_16x16x32_bf16(av, bv, acc[nf], 0, 0, 0);
        }
    }
    #pragma unroll
    for (int nf = 0; nf < 8; ++nf){
        int col = n0 + nf*16 + lr;
        if (col < VV){
            float bb = bout[col];
            #pragma unroll
            for (int r = 0; r < 4; ++r){
                int row = m0 + wave*16 + lh*4 + r;
                out[(size_t)row*VV + col] = acc[nf][r] + bb;
            }
        }
    }
}

extern "C" void kernel_launch(void* const* d_in, const int* in_sizes, int n_in,
                              void* d_out, int out_size, void* d_ws, size_t ws_size,
                              hipStream_t stream) {
    const int*   tok  = (const int*)d_in[0];
    const float* emb  = (const float*)d_in[1];
    const float* W1   = (const float*)d_in[2];
    const float* b1   = (const float*)d_in[3];
    const float* W2   = (const float*)d_in[4];
    const float* b2   = (const float*)d_in[5];
    const float* Wout = (const float*)d_in[6];
    const float* bout = (const float*)d_in[7];
    float* out = (float*)d_out;
    char* ws = (char*)d_ws;

    float* G1    = (float*)(ws);                    // 16,777,216 B
    float* h1a   = (float*)(ws + 16777216);         //  4,194,304 B
    float* h2a   = (float*)(ws + 20971520);         //  4,194,304 B
    float* c1s   = (float*)(ws + 25165824);         //     16,384 B
    float* c2s   = (float*)(ws + 25182208);         //     16,384 B
    u16*   h2b   = (u16*)  (ws + 25198592);         //  2,097,152 B
    u16*   WoutT = (u16*)  (ws + 27295744);         // 25,755,648 B  (total ~50.6 MB)

    hipMemsetAsync(c1s, 0, 32768, stream);  // c1 and c2 state = 0
    cast_transpose_wout<<<dim3(786, 4), 256, 0, stream>>>(Wout, WoutT);
    g1_kernel<<<dim3(64, 16), 256, 0, stream>>>(tok, emb, W1, b1, G1);
    for (int t = 0; t <= TT; ++t)
        step_kernel<<<96, 256, 0, stream>>>(t, G1, W1, W2, b2, h1a, h2a, c1s, c2s, h2b);
    out_gemm<<<25152, 256, 0, stream>>>(h2b, WoutT, bout, out);
}

// Round 2
// 3271.801 us; speedup vs baseline: 1.0095x; 1.0095x over previous
//
#include <hip/hip_runtime.h>
#include <hip/hip_bf16.h>
#include <stdint.h>

#define BB 16
#define TT 256
#define HH 256
#define EE 256
#define GG 1024      // 4*H
#define VV 50257
#define NN 4096      // B*T
#define NBAR 96      // blocks participating in the grid barrier

typedef unsigned short u16;
typedef __attribute__((ext_vector_type(8))) short short8;
typedef __attribute__((ext_vector_type(4))) float f32x4;

__device__ __forceinline__ float sigm(float x){
    float e = __builtin_amdgcn_exp2f(fminf(-x*1.44269504f, 60.0f));
    return 1.0f/(1.0f+e);
}
__device__ __forceinline__ float tanha(float x){
    float e = __builtin_amdgcn_exp2f(fminf(x*2.885390082f, 60.0f));
    return (e-1.0f)/(e+1.0f);
}
__device__ __forceinline__ u16 f2bf(float f){
    uint32_t u = __float_as_uint(f);
    u = (u + 0x7FFFu + ((u>>16)&1u)) >> 16;
    return (u16)u;
}

// ---------------- G1t[t*16+b][g] = b1[g] + sum_e emb[tok[b*T+t]][e] * W1[e][g]
__global__ __launch_bounds__(256) void g1_kernel(const int* __restrict__ tok, const float* __restrict__ emb,
                                                 const float* __restrict__ W1, const float* __restrict__ b1,
                                                 float* __restrict__ G1t){
    __shared__ float xs[64*64];   // X^T[k][n]
    __shared__ float wsm[64*64];  // W[k][g]
    int n0 = blockIdx.x * 64;
    int g0 = blockIdx.y * 64;
    int tid = threadIdx.x;
    int sl = tid & 63;
    int kk = (tid >> 6) * 16;
    int mytok = tok[n0 + sl];
    float acc[4][4] = {};
    int ni = tid & 15, gi = tid >> 4;
    for (int kc = 0; kc < 4; ++kc){
        int k0 = kc*64;
        __syncthreads();
        #pragma unroll
        for (int i4 = 0; i4 < 4; ++i4){
            float4 xv = *(const float4*)(&emb[(size_t)mytok*EE + k0 + kk + i4*4]);
            xs[(kk+i4*4+0)*64 + sl] = xv.x;
            xs[(kk+i4*4+1)*64 + sl] = xv.y;
            xs[(kk+i4*4+2)*64 + sl] = xv.z;
            xs[(kk+i4*4+3)*64 + sl] = xv.w;
        }
        #pragma unroll
        for (int i = 0; i < 16; ++i){
            wsm[(kk+i)*64 + sl] = W1[(size_t)(k0+kk+i)*GG + g0 + sl];
        }
        __syncthreads();
        for (int k = 0; k < 64; ++k){
            float4 av = *(const float4*)(&xs[k*64 + ni*4]);
            float4 bv = *(const float4*)(&wsm[k*64 + gi*4]);
            float a_[4] = {av.x, av.y, av.z, av.w};
            float b_[4] = {bv.x, bv.y, bv.z, bv.w};
            #pragma unroll
            for (int i = 0; i < 4; ++i)
                #pragma unroll
                for (int j = 0; j < 4; ++j)
                    acc[i][j] += a_[i]*b_[j];
        }
    }
    #pragma unroll
    for (int i = 0; i < 4; ++i){
        int n = n0 + ni*4 + i;
        int b = n >> 8;        // tokens are [B,T]: n = b*256 + t
        int tt_ = n & 255;
        float4 o;
        o.x = acc[i][0] + b1[g0+gi*4+0];
        o.y = acc[i][1] + b1[g0+gi*4+1];
        o.z = acc[i][2] + b1[g0+gi*4+2];
        o.w = acc[i][3] + b1[g0+gi*4+3];
        *(float4*)(&G1t[(size_t)(tt_*16 + b)*GG + g0 + gi*4]) = o;
    }
}

// ---------------- persistent kernel: 96 barrier blocks run the LSTM recurrence,
//                  160 extra blocks transpose/cast Wout concurrently.
__global__ __launch_bounds__(256) void persist_kernel(
        const float* __restrict__ G1t, const float* __restrict__ W1,
        const float* __restrict__ W2, const float* __restrict__ b2,
        const float* __restrict__ Wout, u16* __restrict__ WoutT,
        float* __restrict__ h1_all, float* __restrict__ h2_all,
        u16* __restrict__ h2b, int* __restrict__ bar){
    __shared__ float smem[10752];
    float* ubuf = smem;           // staged h (L1: 16x256, L2: 16x512)
    float* red  = smem + 8192;    // reduction scratch (2048)
    float* gmat = smem + 10240;   // gate matrix (512)
    int bid = blockIdx.x;
    int tid = threadIdx.x;

    if (bid >= NBAR){
        // ---- Wout cast + transpose worker (no barrier participation)
        u16* tile = (u16*)smem;   // [64][65]
        int r  = tid >> 2;
        int cq = tid & 3;
        for (int tau = bid - NBAR; tau < 786*4; tau += 160){
            int ky = tau / 786;
            int nx = tau - ky*786;
            int n0 = nx*64, k0 = ky*64;
            #pragma unroll
            for (int i = 0; i < 16; ++i){
                int n = n0 + cq*16 + i;
                float v = (n < VV) ? Wout[(size_t)(k0 + r)*VV + n] : 0.0f;
                tile[(cq*16 + i)*65 + r] = f2bf(v);
            }
            __syncthreads();
            #pragma unroll
            for (int i4 = 0; i4 < 4; ++i4){
                int kl = cq*16 + i4*4;
                uint2 v;
                v.x = (uint32_t)tile[r*65 + kl+0] | ((uint32_t)tile[r*65 + kl+1] << 16);
                v.y = (uint32_t)tile[r*65 + kl+2] | ((uint32_t)tile[r*65 + kl+3] << 16);
                *(uint2*)(&WoutT[(size_t)(n0 + r)*256 + k0 + kl]) = v;
            }
            __syncthreads();
        }
        return;
    }

    if (bid < 32){
        // ================= L1 role: gates = G1t[t] + h1_{t-1} @ W1[256:512]
        int w  = bid;         // owns hidden cols w*8 .. w*8+7
        int rc = tid >> 4;    // 0..15  row-chunk
        int cg = tid & 15;    // 0..15  col-group
        int cb  = tid >> 4;
        int ccg = tid & 15;
        float wreg[2][16];
        int gc_c[2];
        #pragma unroll
        for (int j = 0; j < 2; ++j){
            int gl = cg*2 + j;
            int gc = (gl>>3)*HH + w*8 + (gl&7);
            #pragma unroll
            for (int i = 0; i < 16; ++i)
                wreg[j][i] = W1[(size_t)(HH + rc*16 + i)*GG + gc];
            int gl2 = ccg*2 + j;
            gc_c[j] = (gl2>>3)*HH + w*8 + (gl2&7);
        }
        bool act = (tid < 128);
        int ab = tid >> 3, acl = tid & 7;
        float creg = 0.0f;

        for (int it = 0; it <= TT; ++it){
            if (it < TT){
                int t = it;
                float g1v[2];
                #pragma unroll
                for (int j = 0; j < 2; ++j)
                    g1v[j] = G1t[((size_t)t*16 + cb)*GG + gc_c[j]];
                if (t > 0){
                    const float4* src = (const float4*)(h1_all + (size_t)(t-1)*(BB*HH));
                    float4* dst = (float4*)ubuf;
                    #pragma unroll
                    for (int j = 0; j < 4; ++j) dst[j*256 + tid] = src[j*256 + tid];
                }
                __syncthreads();
                float pp[2][16] = {};
                if (t > 0){
                    #pragma unroll
                    for (int b = 0; b < 16; ++b){
                        const float4* hp4 = (const float4*)(ubuf + b*256 + rc*16);
                        float4 h0 = hp4[0], h1v = hp4[1], h2v = hp4[2], h3v = hp4[3];
                        float hv[16] = {h0.x,h0.y,h0.z,h0.w, h1v.x,h1v.y,h1v.z,h1v.w,
                                        h2v.x,h2v.y,h2v.z,h2v.w, h3v.x,h3v.y,h3v.z,h3v.w};
                        #pragma unroll
                        for (int i = 0; i < 16; ++i){
                            pp[0][b] += hv[i]*wreg[0][i];
                            pp[1][b] += hv[i]*wreg[1][i];
                        }
                    }
                }
                #pragma unroll
                for (int m = 16; m <= 32; m <<= 1){
                    #pragma unroll
                    for (int j = 0; j < 2; ++j)
                        #pragma unroll
                        for (int b = 0; b < 16; ++b)
                            pp[j][b] += __shfl_xor(pp[j][b], m, 64);
                }
                int wave = tid >> 6;
                if ((tid & 0x30) == 0){
                    #pragma unroll
                    for (int j = 0; j < 2; ++j)
                        #pragma unroll
                        for (int b = 0; b < 16; ++b)
                            red[((wave*16 + cg)*2 + j)*16 + b] = pp[j][b];
                }
                __syncthreads();
                #pragma unroll
                for (int j = 0; j < 2; ++j){
                    float s = g1v[j];
                    #pragma unroll
                    for (int wv = 0; wv < 4; ++wv) s += red[((wv*16 + ccg)*2 + j)*16 + cb];
                    gmat[cb*32 + ccg*2 + j] = s;
                }
                __syncthreads();
                if (act){
                    float gi_ = gmat[ab*32 + acl];
                    float gj_ = gmat[ab*32 + 8  + acl];
                    float gf_ = gmat[ab*32 + 16 + acl];
                    float go_ = gmat[ab*32 + 24 + acl];
                    float cn = creg * sigm(gf_ + 1.0f) + sigm(gi_) * tanha(gj_);
                    float hn = tanha(cn) * sigm(go_);
                    creg = cn;
                    h1_all[(size_t)t*(BB*HH) + ab*HH + w*8 + acl] = hn;
                }
            }
            if (it < TT){
                __syncthreads();
                if (tid == 0){
                    __hip_atomic_fetch_add(&bar[it], 1, __ATOMIC_RELEASE, __HIP_MEMORY_SCOPE_AGENT);
                    while (__hip_atomic_load(&bar[it], __ATOMIC_ACQUIRE, __HIP_MEMORY_SCOPE_AGENT) < NBAR)
                        __builtin_amdgcn_s_sleep(1);
                }
                __syncthreads();
            }
        }
    } else {
        // ================= L2 role: gates = b2 + [h1_t ; h2_{t-1}] @ W2
        int w2 = bid - 32;    // owns hidden cols w2*4 .. w2*4+3
        int rc = tid >> 3;    // 0..31
        int cg = tid & 7;     // 0..7
        int cb  = tid >> 4;   // 0..15
        int cgl = tid & 15;   // gl 0..15
        float b2v = b2[(cgl>>2)*HH + w2*4 + (cgl&3)];
        float wreg[2][16];
        #pragma unroll
        for (int j = 0; j < 2; ++j){
            int gl = cg*2 + j;
            int gc = (gl>>2)*HH + w2*4 + (gl&3);
            #pragma unroll
            for (int i = 0; i < 16; ++i)
                wreg[j][i] = W2[(size_t)(rc*16 + i)*GG + gc];
        }
        bool act = (tid < 64);
        int ab = tid >> 2, acl = tid & 3;
        float creg = 0.0f;

        for (int it = 0; it <= TT; ++it){
            if (it >= 1){
                int tt = it - 1;
                {
                    const float4* s1 = (const float4*)(h1_all + (size_t)tt*(BB*HH));
                    float4* dst = (float4*)ubuf;
                    #pragma unroll
                    for (int j = 0; j < 4; ++j){
                        int flat = j*256 + tid;
                        int b = flat >> 6, r4 = flat & 63;
                        dst[b*128 + r4] = s1[flat];
                    }
                    if (tt > 0){
                        const float4* s2 = (const float4*)h2_all;
                        #pragma unroll
                        for (int j = 0; j < 4; ++j){
                            int flat = j*256 + tid;
                            int b = flat >> 6, r4 = flat & 63;
                            dst[b*128 + 64 + r4] = s2[((size_t)b*TT + (tt-1))*64 + r4];
                        }
                    } else {
                        float4 z = {0.f,0.f,0.f,0.f};
                        #pragma unroll
                        for (int j = 0; j < 4; ++j){
                            int flat = j*256 + tid;
                            int b = flat >> 6, r4 = flat & 63;
                            dst[b*128 + 64 + r4] = z;
                        }
                    }
                }
                __syncthreads();
                float pp[2][16] = {};
                #pragma unroll
                for (int b = 0; b < 16; ++b){
                    const float4* up4 = (const float4*)(ubuf + b*512 + rc*16);
                    float4 u0 = up4[0], u1 = up4[1], u2 = up4[2], u3 = up4[3];
                    float uv[16] = {u0.x,u0.y,u0.z,u0.w, u1.x,u1.y,u1.z,u1.w,
                                    u2.x,u2.y,u2.z,u2.w, u3.x,u3.y,u3.z,u3.w};
                    #pragma unroll
                    for (int i = 0; i < 16; ++i){
                        pp[0][b] += uv[i]*wreg[0][i];
                        pp[1][b] += uv[i]*wreg[1][i];
                    }
                }
                #pragma unroll
                for (int m = 8; m <= 32; m <<= 1){
                    #pragma unroll
                    for (int j = 0; j < 2; ++j)
                        #pragma unroll
                        for (int b = 0; b < 16; ++b)
                            pp[j][b] += __shfl_xor(pp[j][b], m, 64);
                }
                int wave = tid >> 6;
                if ((tid & 0x38) == 0){
                    #pragma unroll
                    for (int j = 0; j < 2; ++j)
                        #pragma unroll
                        for (int b = 0; b < 16; ++b)
                            red[((wave*8 + cg)*2 + j)*16 + b] = pp[j][b];
                }
                __syncthreads();
                {
                    float s = b2v;
                    #pragma unroll
                    for (int wv = 0; wv < 4; ++wv) s += red[((wv*8 + (cgl>>1))*2 + (cgl&1))*16 + cb];
                    gmat[cb*16 + cgl] = s;
                }
                __syncthreads();
                if (act){
                    float gi_ = gmat[ab*16 + acl];
                    float gj_ = gmat[ab*16 + 4  + acl];
                    float gf_ = gmat[ab*16 + 8  + acl];
                    float go_ = gmat[ab*16 + 12 + acl];
                    float cn = creg * sigm(gf_ + 1.0f) + sigm(gi_) * tanha(gj_);
                    float hn = tanha(cn) * sigm(go_);
                    creg = cn;
                    int c = w2*4 + acl;
                    size_t oi = ((size_t)ab*TT + tt)*HH + c;
                    h2_all[oi] = hn;
                    h2b[oi] = f2bf(hn);
                }
            }
            if (it < TT){
                __syncthreads();
                if (tid == 0){
                    __hip_atomic_fetch_add(&bar[it], 1, __ATOMIC_RELEASE, __HIP_MEMORY_SCOPE_AGENT);
                    while (__hip_atomic_load(&bar[it], __ATOMIC_ACQUIRE, __HIP_MEMORY_SCOPE_AGENT) < NBAR)
                        __builtin_amdgcn_s_sleep(1);
                }
                __syncthreads();
            }
        }
    }
}

// ---------------- out = h2b[4096,256] @ WoutT^T + bout   (bf16 MFMA, fp32 accumulate)
__global__ __launch_bounds__(256) void out_gemm(const u16* __restrict__ A, const u16* __restrict__ Bt,
                                                const float* __restrict__ bout, float* __restrict__ out){
    int bx = blockIdx.x;
    int mb = bx & 63;      // 64 m-tiles of 64
    int nb = bx >> 6;      // 393 n-tiles of 128
    int m0 = mb*64, n0 = nb*128;
    int tid = threadIdx.x;
    int wave = tid >> 6, lane = tid & 63;
    int lr = lane & 15, lh = lane >> 4;
    f32x4 acc[8];
    #pragma unroll
    for (int nf = 0; nf < 8; ++nf) acc[nf] = (f32x4){0.f,0.f,0.f,0.f};
    const short8* Ap = (const short8*)(A + (size_t)(m0 + wave*16 + lr)*256);
    #pragma unroll
    for (int ks = 0; ks < 8; ++ks){
        short8 av = Ap[ks*4 + lh];
        #pragma unroll
        for (int nf = 0; nf < 8; ++nf){
            const short8* Bp = (const short8*)(Bt + (size_t)(n0 + nf*16 + lr)*256);
            short8 bv = Bp[ks*4 + lh];
            acc[nf] = __builtin_amdgcn_mfma_f32_16x16x32_bf16(av, bv, acc[nf], 0, 0, 0);
        }
    }
    #pragma unroll
    for (int nf = 0; nf < 8; ++nf){
        int col = n0 + nf*16 + lr;
        if (col < VV){
            float bb = bout[col];
            #pragma unroll
            for (int r = 0; r < 4; ++r){
                int row = m0 + wave*16 + lh*4 + r;
                out[(size_t)row*VV + col] = acc[nf][r] + bb;
            }
        }
    }
}

extern "C" void kernel_launch(void* const* d_in, const int* in_sizes, int n_in,
                              void* d_out, int out_size, void* d_ws, size_t ws_size,
                              hipStream_t stream) {
    const int*   tok  = (const int*)d_in[0];
    const float* emb  = (const float*)d_in[1];
    const float* W1   = (const float*)d_in[2];
    const float* b1   = (const float*)d_in[3];
    const float* W2   = (const float*)d_in[4];
    const float* b2   = (const float*)d_in[5];
    const float* Wout = (const float*)d_in[6];
    const float* bout = (const float*)d_in[7];
    float* out = (float*)d_out;
    char* ws = (char*)d_ws;

    float* G1t   = (float*)(ws);                    // 16,777,216 B
    float* h1a   = (float*)(ws + 16777216);         //  4,194,304 B
    float* h2a   = (float*)(ws + 20971520);         //  4,194,304 B
    u16*   h2b   = (u16*)  (ws + 25165824);         //  2,097,152 B
    u16*   WoutT = (u16*)  (ws + 27262976);         // 25,755,648 B (end ~53 MB)
    int*   bar   = (int*)d_out;                     // 256 counters; overwritten by out_gemm

    hipMemsetAsync(d_out, 0, 2048, stream);
    g1_kernel<<<dim3(64, 16), 256, 0, stream>>>(tok, emb, W1, b1, G1t);
    persist_kernel<<<256, 256, 0, stream>>>(G1t, W1, W2, b2, Wout, WoutT,
                                            h1a, h2a, h2b, bar);
    out_gemm<<<25152, 256, 0, stream>>>(h2b, WoutT, bout, out);
}

// Round 3
// 1512.354 us; speedup vs baseline: 2.1840x; 2.1634x over previous
//
#include <hip/hip_runtime.h>
#include <hip/hip_bf16.h>
#include <stdint.h>

#define BB 16
#define TT 256
#define HH 256
#define EE 256
#define GG 1024      // 4*H
#define VV 50257
#define NN 4096      // B*T

typedef unsigned short u16;
typedef __attribute__((ext_vector_type(8))) short short8;
typedef __attribute__((ext_vector_type(4))) float f32x4;

__device__ __forceinline__ float sigm(float x){
    float e = __builtin_amdgcn_exp2f(fminf(-x*1.44269504f, 60.0f));
    return 1.0f/(1.0f+e);
}
__device__ __forceinline__ float tanha(float x){
    float e = __builtin_amdgcn_exp2f(fminf(x*2.885390082f, 60.0f));
    return (e-1.0f)/(e+1.0f);
}
__device__ __forceinline__ u16 f2bf(float f){
    uint32_t u = __float_as_uint(f);
    u = (u + 0x7FFFu + ((u>>16)&1u)) >> 16;
    return (u16)u;
}
// device-coherent (agent-scope, sc0|sc1) data movement — no fence maintenance ops
__device__ __forceinline__ float ld_coh(const float* p){
    int v = __hip_atomic_load((int*)p, __ATOMIC_RELAXED, __HIP_MEMORY_SCOPE_AGENT);
    return __int_as_float(v);
}
__device__ __forceinline__ void st_coh(float* p, float v){
    __hip_atomic_store((int*)p, __float_as_int(v), __ATOMIC_RELAXED, __HIP_MEMORY_SCOPE_AGENT);
}
__device__ __forceinline__ void poll_ge(int* p, int want){
    while (__hip_atomic_load(p, __ATOMIC_RELAXED, __HIP_MEMORY_SCOPE_AGENT) < want)
        __builtin_amdgcn_s_sleep(2);
}

// ---------------- G1t[(t*16+b)][g] = b1[g] + sum_e emb[tok[b*T+t]][e] * W1[e][g]
__global__ __launch_bounds__(256) void g1_kernel(const int* __restrict__ tok, const float* __restrict__ emb,
                                                 const float* __restrict__ W1, const float* __restrict__ b1,
                                                 float* __restrict__ G1t){
    __shared__ float xs[64*64];
    __shared__ float wsm[64*64];
    int n0 = blockIdx.x * 64;
    int g0 = blockIdx.y * 64;
    int tid = threadIdx.x;
    int sl = tid & 63;
    int kk = (tid >> 6) * 16;
    int mytok = tok[n0 + sl];
    float acc[4][4] = {};
    int ni = tid & 15, gi = tid >> 4;
    for (int kc = 0; kc < 4; ++kc){
        int k0 = kc*64;
        __syncthreads();
        #pragma unroll
        for (int i4 = 0; i4 < 4; ++i4){
            float4 xv = *(const float4*)(&emb[(size_t)mytok*EE + k0 + kk + i4*4]);
            xs[(kk+i4*4+0)*64 + sl] = xv.x;
            xs[(kk+i4*4+1)*64 + sl] = xv.y;
            xs[(kk+i4*4+2)*64 + sl] = xv.z;
            xs[(kk+i4*4+3)*64 + sl] = xv.w;
        }
        #pragma unroll
        for (int i = 0; i < 16; ++i){
            wsm[(kk+i)*64 + sl] = W1[(size_t)(k0+kk+i)*GG + g0 + sl];
        }
        __syncthreads();
        for (int k = 0; k < 64; ++k){
            float4 av = *(const float4*)(&xs[k*64 + ni*4]);
            float4 bv = *(const float4*)(&wsm[k*64 + gi*4]);
            float a_[4] = {av.x, av.y, av.z, av.w};
            float b_[4] = {bv.x, bv.y, bv.z, bv.w};
            #pragma unroll
            for (int i = 0; i < 4; ++i)
                #pragma unroll
                for (int j = 0; j < 4; ++j)
                    acc[i][j] += a_[i]*b_[j];
        }
    }
    #pragma unroll
    for (int i = 0; i < 4; ++i){
        int n = n0 + ni*4 + i;
        int b = n >> 8;
        int tt_ = n & 255;
        float4 o;
        o.x = acc[i][0] + b1[g0+gi*4+0];
        o.y = acc[i][1] + b1[g0+gi*4+1];
        o.z = acc[i][2] + b1[g0+gi*4+2];
        o.w = acc[i][3] + b1[g0+gi*4+3];
        *(float4*)(&G1t[(size_t)(tt_*16 + b)*GG + g0 + gi*4]) = o;
    }
}

// ---------------- persistent: 96 recurrence blocks (8 groups x (4 L1 + 8 L2)), 128 transpose workers
__global__ __launch_bounds__(1024) void persist_kernel(
        const float* __restrict__ G1t, const float* __restrict__ W1,
        const float* __restrict__ W2, const float* __restrict__ b2,
        const float* __restrict__ Wout, u16* __restrict__ WoutT,
        float* __restrict__ h1x, float* __restrict__ h2x,
        u16* __restrict__ h2b, int* __restrict__ ctrA, int* __restrict__ ctrB){
    __shared__ __align__(16) char smem[12288];
    const int bid = blockIdx.x;
    const int tid = threadIdx.x;

    if (bid >= 96){
        // ---- Wout cast+transpose workers: Wout[256][50257] f32 -> WoutT[50304][256] bf16
        u16* tile = (u16*)smem;   // [64][66]
        const int r = tid >> 4, i = tid & 15;
        for (int tau = bid - 96; tau < 786*4; tau += 128){
            int ky = tau / 786;
            int nx = tau - ky*786;
            int n0 = nx*64, k0 = ky*64;
            #pragma unroll
            for (int jj = 0; jj < 4; ++jj){
                int n = n0 + i*4 + jj;
                float f = (n < VV) ? Wout[(size_t)(k0 + r)*VV + n] : 0.0f;
                tile[(i*4 + jj)*66 + r] = f2bf(f);
            }
            __syncthreads();
            {
                int kl = i*4;
                uint2 v;
                v.x = (uint32_t)tile[r*66 + kl+0] | ((uint32_t)tile[r*66 + kl+1] << 16);
                v.y = (uint32_t)tile[r*66 + kl+2] | ((uint32_t)tile[r*66 + kl+3] << 16);
                *(uint2*)(&WoutT[(size_t)(n0 + r)*256 + k0 + kl]) = v;
            }
            __syncthreads();
        }
        return;
    }

    const int g  = bid & 7;    // group (2 batches: 2g, 2g+1); same XCD per group (round-robin heuristic)
    const int rr = bid >> 3;   // 0..3 = L1 slice, 4..11 = L2 slice
    const int l  = tid & 63;
    const int wv = tid >> 6;
    int* myA = ctrA + g*TT;
    int* myB = ctrB + g*TT;

    if (rr < 4){
        // ========== L1: gates[2, 256cols] = G1t + h1_{t-1} @ W1rec   (block owns units 64*r1..+64)
        const int r1 = rr;
        const int gate = wv >> 2, usub = wv & 3;
        const int colw = gate*HH + 64*r1 + 16*usub;
        short8 wf[8];
        {
            const int col = colw + (l & 15);
            const int kb = (l >> 4) << 3;
            #pragma unroll
            for (int kk = 0; kk < 8; ++kk){
                short8 s;
                #pragma unroll
                for (int j = 0; j < 8; ++j)
                    s[j] = (short)f2bf(W1[(size_t)(HH + kk*32 + kb + j)*GG + col]);
                wf[kk] = s;
            }
        }
        u16*  hA = (u16*)smem;               // [2][256] bf16
        float* gm = (float*)(smem + 1024);   // [4][64][2] f32
        float creg = 0.f;
        const int au = tid >> 1, ab = tid & 1;

        for (int t = 0; t < TT; ++t){
            float c0 = 0.f, c1 = 0.f;
            if (l < 16){
                c0 = G1t[((size_t)t*BB + 2*g + 0)*GG + colw + l];
                c1 = G1t[((size_t)t*BB + 2*g + 1)*GG + colw + l];
            }
            f32x4 acc = {c0, c1, 0.f, 0.f};
            if (t > 0){
                poll_ge(&myA[t-1], 4);
                if (tid < 512){
                    int b = tid >> 8, u = tid & 255;
                    float hv = ld_coh(&h1x[((size_t)(t-1)*BB + 2*g + b)*HH + u]);
                    hA[b*256 + u] = f2bf(hv);
                }
                __syncthreads();
                const u16* ap = hA + (l & 1)*256 + ((l >> 4) << 3);
                #pragma unroll
                for (int kk = 0; kk < 8; ++kk)
                    acc = __builtin_amdgcn_mfma_f32_16x16x32_bf16(
                            *(const short8*)(ap + kk*32), wf[kk], acc, 0, 0, 0);
            }
            if (l < 16){
                gm[(gate*64 + usub*16 + l)*2 + 0] = acc[0];
                gm[(gate*64 + usub*16 + l)*2 + 1] = acc[1];
            }
            __syncthreads();
            if (tid < 128){
                float gi_ = gm[(0*64 + au)*2 + ab];
                float gj_ = gm[(1*64 + au)*2 + ab];
                float gf_ = gm[(2*64 + au)*2 + ab];
                float go_ = gm[(3*64 + au)*2 + ab];
                float cn = creg * sigm(gf_ + 1.0f) + sigm(gi_)*tanha(gj_);
                float hn = tanha(cn)*sigm(go_);
                creg = cn;
                st_coh(&h1x[((size_t)t*BB + 2*g + ab)*HH + 64*r1 + au], hn);
            }
            __syncthreads();   // drains vmcnt of all waves before flag
            if (tid == 0)
                __hip_atomic_fetch_add(&myA[t], 1, __ATOMIC_RELAXED, __HIP_MEMORY_SCOPE_AGENT);
        }
    } else {
        // ========== L2: gates[2, 128cols] = b2 + [h1_t ; h2_{t-1}] @ W2   (block owns units 32*r2..+32)
        const int r2 = rr - 4;
        const int nt = wv >> 1, kh = wv & 1;
        const int gate = nt >> 1, usub = nt & 1;
        const int colw = gate*HH + 32*r2 + 16*usub;
        short8 wf[8];
        {
            const int col = colw + (l & 15);
            const int kb = (l >> 4) << 3;
            #pragma unroll
            for (int kk = 0; kk < 8; ++kk){
                short8 s;
                #pragma unroll
                for (int j = 0; j < 8; ++j)
                    s[j] = (short)f2bf(W2[(size_t)(kh*256 + kk*32 + kb + j)*GG + col]);
                wf[kk] = s;
            }
        }
        u16*  uB = (u16*)smem;               // [2][512] bf16
        float* gm = (float*)(smem + 2048);   // [4][32][2][2] f32
        float creg = 0.f;
        const int au = tid >> 1, ab = tid & 1;
        float bv0 = 0.f, bv1 = 0.f, bv2 = 0.f, bv3 = 0.f;
        if (tid < 64){
            bv0 = b2[0*HH + 32*r2 + au];
            bv1 = b2[1*HH + 32*r2 + au];
            bv2 = b2[2*HH + 32*r2 + au];
            bv3 = b2[3*HH + 32*r2 + au];
        }

        for (int it = 1; it <= TT; ++it){
            const int tt = it - 1;
            poll_ge(&myA[tt], 4);
            if (tt > 0) poll_ge(&myB[tt-1], 8);
            {
                int z = tid >> 9, b = (tid >> 8) & 1, u = tid & 255;
                float v = 0.f;
                if (z == 0)           v = ld_coh(&h1x[((size_t)tt*BB + 2*g + b)*HH + u]);
                else if (tt > 0)      v = ld_coh(&h2x[((size_t)(tt-1)*BB + 2*g + b)*HH + u]);
                uB[b*512 + z*256 + u] = f2bf(v);
            }
            __syncthreads();
            f32x4 acc = {0.f, 0.f, 0.f, 0.f};
            const u16* ap = uB + (l & 1)*512 + kh*256 + ((l >> 4) << 3);
            #pragma unroll
            for (int kk = 0; kk < 8; ++kk)
                acc = __builtin_amdgcn_mfma_f32_16x16x32_bf16(
                        *(const short8*)(ap + kk*32), wf[kk], acc, 0, 0, 0);
            if (l < 16){
                gm[((gate*32 + usub*16 + l)*2 + 0)*2 + kh] = acc[0];
                gm[((gate*32 + usub*16 + l)*2 + 1)*2 + kh] = acc[1];
            }
            __syncthreads();
            if (tid < 64){
                float gi_ = gm[((0*32 + au)*2 + ab)*2 + 0] + gm[((0*32 + au)*2 + ab)*2 + 1] + bv0;
                float gj_ = gm[((1*32 + au)*2 + ab)*2 + 0] + gm[((1*32 + au)*2 + ab)*2 + 1] + bv1;
                float gf_ = gm[((2*32 + au)*2 + ab)*2 + 0] + gm[((2*32 + au)*2 + ab)*2 + 1] + bv2;
                float go_ = gm[((3*32 + au)*2 + ab)*2 + 0] + gm[((3*32 + au)*2 + ab)*2 + 1] + bv3;
                float cn = creg * sigm(gf_ + 1.0f) + sigm(gi_)*tanha(gj_);
                float hn = tanha(cn)*sigm(go_);
                creg = cn;
                st_coh(&h2x[((size_t)tt*BB + 2*g + ab)*HH + 32*r2 + au], hn);
                h2b[((size_t)(2*g + ab)*TT + tt)*HH + 32*r2 + au] = f2bf(hn);
            }
            __syncthreads();   // drains vmcnt before flag
            if (tid == 0)
                __hip_atomic_fetch_add(&myB[tt], 1, __ATOMIC_RELAXED, __HIP_MEMORY_SCOPE_AGENT);
        }
    }
}

// ---------------- out = h2b[4096,256] @ WoutT^T + bout   (bf16 MFMA, fp32 accumulate)
__global__ __launch_bounds__(256) void out_gemm(const u16* __restrict__ A, const u16* __restrict__ Bt,
                                                const float* __restrict__ bout, float* __restrict__ out){
    int bx = blockIdx.x;
    int mb = bx & 63;
    int nb = bx >> 6;
    int m0 = mb*64, n0 = nb*128;
    int tid = threadIdx.x;
    int wave = tid >> 6, lane = tid & 63;
    int lr = lane & 15, lh = lane >> 4;
    f32x4 acc[8];
    #pragma unroll
    for (int nf = 0; nf < 8; ++nf) acc[nf] = (f32x4){0.f,0.f,0.f,0.f};
    const short8* Ap = (const short8*)(A + (size_t)(m0 + wave*16 + lr)*256);
    #pragma unroll
    for (int ks = 0; ks < 8; ++ks){
        short8 av = Ap[ks*4 + lh];
        #pragma unroll
        for (int nf = 0; nf < 8; ++nf){
            const short8* Bp = (const short8*)(Bt + (size_t)(n0 + nf*16 + lr)*256);
            short8 bv = Bp[ks*4 + lh];
            acc[nf] = __builtin_amdgcn_mfma_f32_16x16x32_bf16(av, bv, acc[nf], 0, 0, 0);
        }
    }
    #pragma unroll
    for (int nf = 0; nf < 8; ++nf){
        int col = n0 + nf*16 + lr;
        if (col < VV){
            float bb = bout[col];
            #pragma unroll
            for (int r = 0; r < 4; ++r){
                int row = m0 + wave*16 + lh*4 + r;
                out[(size_t)row*VV + col] = acc[nf][r] + bb;
            }
        }
    }
}

extern "C" void kernel_launch(void* const* d_in, const int* in_sizes, int n_in,
                              void* d_out, int out_size, void* d_ws, size_t ws_size,
                              hipStream_t stream) {
    const int*   tok  = (const int*)d_in[0];
    const float* emb  = (const float*)d_in[1];
    const float* W1   = (const float*)d_in[2];
    const float* b1   = (const float*)d_in[3];
    const float* W2   = (const float*)d_in[4];
    const float* b2   = (const float*)d_in[5];
    const float* Wout = (const float*)d_in[6];
    const float* bout = (const float*)d_in[7];
    float* out = (float*)d_out;
    char* ws = (char*)d_ws;

    int*   ctrA  = (int*)(ws);                          //  8,192 B  [8][256]
    int*   ctrB  = (int*)(ws + 8192);                   //  8,192 B  [8][256]
    float* G1t   = (float*)(ws + 32768);                // 16,777,216 B  [T*16][1024]
    float* h1x   = (float*)(ws + 32768 + 16777216);     //  4,194,304 B  [T][16][256]
    float* h2x   = (float*)(ws + 32768 + 20971520);     //  4,194,304 B  [T][16][256]
    u16*   h2b   = (u16*)  (ws + 32768 + 25165824);     //  2,097,152 B  [16][T][256]
    u16*   WoutT = (u16*)  (ws + 32768 + 27262976);     // 25,755,648 B  [50304][256]

    hipMemsetAsync(ws, 0, 32768, stream);   // zero step counters (replay-safe)
    g1_kernel<<<dim3(64, 16), 256, 0, stream>>>(tok, emb, W1, b1, G1t);
    persist_kernel<<<224, 1024, 0, stream>>>(G1t, W1, W2, b2, Wout, WoutT,
                                             h1x, h2x, h2b, ctrA, ctrB);
    out_gemm<<<25152, 256, 0, stream>>>(h2b, WoutT, bout, out);
}

// Round 4
// 1114.353 us; speedup vs baseline: 2.9640x; 1.3572x over previous
//
#include <hip/hip_runtime.h>
#include <hip/hip_bf16.h>
#include <stdint.h>

#define BB 16
#define TT 256
#define HH 256
#define EE 256
#define GG 1024      // 4*H
#define VV 50257
#define NN 4096      // B*T

typedef unsigned short u16;
typedef __attribute__((ext_vector_type(8))) short short8;
typedef __attribute__((ext_vector_type(4))) float f32x4;

__device__ __forceinline__ float sigm(float x){
    float e = __builtin_amdgcn_exp2f(fminf(-x*1.44269504f, 60.0f));
    return 1.0f/(1.0f+e);
}
__device__ __forceinline__ float tanha(float x){
    float e = __builtin_amdgcn_exp2f(fminf(x*2.885390082f, 60.0f));
    return (e-1.0f)/(e+1.0f);
}
__device__ __forceinline__ u16 f2bf(float f){
    uint32_t u = __float_as_uint(f);
    u = (u + 0x7FFFu + ((u>>16)&1u)) >> 16;
    return (u16)u;
}
// device-coherent (agent-scope) data movement
__device__ __forceinline__ float ld_coh(const float* p){
    int v = __hip_atomic_load((int*)p, __ATOMIC_RELAXED, __HIP_MEMORY_SCOPE_AGENT);
    return __int_as_float(v);
}
__device__ __forceinline__ void st_coh(float* p, float v){
    __hip_atomic_store((int*)p, __float_as_int(v), __ATOMIC_RELAXED, __HIP_MEMORY_SCOPE_AGENT);
}
__device__ __forceinline__ void poll_ge(int* p, int want){
    while (__hip_atomic_load(p, __ATOMIC_RELAXED, __HIP_MEMORY_SCOPE_AGENT) < want)
        __builtin_amdgcn_s_sleep(2);
}
__device__ __forceinline__ void gl_lds16(const void* g, void* s){
    __builtin_amdgcn_global_load_lds((const __attribute__((address_space(1))) unsigned int*)g,
                                     (__attribute__((address_space(3))) unsigned int*)s, 16, 0, 0);
}

// ---------------- G1t[(t*16+b)][g] = b1[g] + sum_e emb[tok[b*T+t]][e] * W1[e][g]
__global__ __launch_bounds__(256) void g1_kernel(const int* __restrict__ tok, const float* __restrict__ emb,
                                                 const float* __restrict__ W1, const float* __restrict__ b1,
                                                 float* __restrict__ G1t){
    __shared__ float xs[64*64];
    __shared__ float wsm[64*64];
    int n0 = blockIdx.x * 64;
    int g0 = blockIdx.y * 64;
    int tid = threadIdx.x;
    int sl = tid & 63;
    int kk = (tid >> 6) * 16;
    int mytok = tok[n0 + sl];
    float acc[4][4] = {};
    int ni = tid & 15, gi = tid >> 4;
    for (int kc = 0; kc < 4; ++kc){
        int k0 = kc*64;
        __syncthreads();
        #pragma unroll
        for (int i4 = 0; i4 < 4; ++i4){
            float4 xv = *(const float4*)(&emb[(size_t)mytok*EE + k0 + kk + i4*4]);
            xs[(kk+i4*4+0)*64 + sl] = xv.x;
            xs[(kk+i4*4+1)*64 + sl] = xv.y;
            xs[(kk+i4*4+2)*64 + sl] = xv.z;
            xs[(kk+i4*4+3)*64 + sl] = xv.w;
        }
        #pragma unroll
        for (int i = 0; i < 16; ++i){
            wsm[(kk+i)*64 + sl] = W1[(size_t)(k0+kk+i)*GG + g0 + sl];
        }
        __syncthreads();
        for (int k = 0; k < 64; ++k){
            float4 av = *(const float4*)(&xs[k*64 + ni*4]);
            float4 bv = *(const float4*)(&wsm[k*64 + gi*4]);
            float a_[4] = {av.x, av.y, av.z, av.w};
            float b_[4] = {bv.x, bv.y, bv.z, bv.w};
            #pragma unroll
            for (int i = 0; i < 4; ++i)
                #pragma unroll
                for (int j = 0; j < 4; ++j)
                    acc[i][j] += a_[i]*b_[j];
        }
    }
    #pragma unroll
    for (int i = 0; i < 4; ++i){
        int n = n0 + ni*4 + i;
        int b = n >> 8;
        int tt_ = n & 255;
        float4 o;
        o.x = acc[i][0] + b1[g0+gi*4+0];
        o.y = acc[i][1] + b1[g0+gi*4+1];
        o.z = acc[i][2] + b1[g0+gi*4+2];
        o.w = acc[i][3] + b1[g0+gi*4+3];
        *(float4*)(&G1t[(size_t)(tt_*16 + b)*GG + g0 + gi*4]) = o;
    }
}

// ---------------- persistent: 96 recurrence blocks (8 groups x (4 L1 + 8 L2)), 128 transpose workers
__global__ __launch_bounds__(1024) void persist_kernel(
        const float* __restrict__ G1t, const float* __restrict__ W1,
        const float* __restrict__ W2, const float* __restrict__ b2,
        const float* __restrict__ Wout, u16* __restrict__ WoutT,
        float* __restrict__ h1x, float* __restrict__ h2x,
        u16* __restrict__ h2b, int* __restrict__ ctrA, int* __restrict__ ctrB){
    __shared__ __align__(16) char smem[12288];
    const int bid = blockIdx.x;
    const int tid = threadIdx.x;

    if (bid >= 96){
        // ---- Wout cast+transpose workers: Wout[256][50257] f32 -> WoutT[50304][256] bf16
        u16* tile = (u16*)smem;   // [64][66]
        const int r = tid >> 4, i = tid & 15;
        for (int tau = bid - 96; tau < 786*4; tau += 128){
            int ky = tau / 786;
            int nx = tau - ky*786;
            int n0 = nx*64, k0 = ky*64;
            #pragma unroll
            for (int jj = 0; jj < 4; ++jj){
                int n = n0 + i*4 + jj;
                float f = (n < VV) ? Wout[(size_t)(k0 + r)*VV + n] : 0.0f;
                tile[(i*4 + jj)*66 + r] = f2bf(f);
            }
            __syncthreads();
            {
                int kl = i*4;
                uint2 v;
                v.x = (uint32_t)tile[r*66 + kl+0] | ((uint32_t)tile[r*66 + kl+1] << 16);
                v.y = (uint32_t)tile[r*66 + kl+2] | ((uint32_t)tile[r*66 + kl+3] << 16);
                *(uint2*)(&WoutT[(size_t)(n0 + r)*256 + k0 + kl]) = v;
            }
            __syncthreads();
        }
        return;
    }

    const int g  = bid & 7;    // group (2 batches: 2g, 2g+1)
    const int rr = bid >> 3;   // 0..3 = L1 slice, 4..11 = L2 slice
    const int l  = tid & 63;
    const int wv = tid >> 6;
    int* myA = ctrA + g*TT;
    int* myB = ctrB + g*TT;

    if (rr < 4){
        // ========== L1: gates[2, 256cols] = G1t + h1_{t-1} @ W1rec   (block owns units 64*r1..+64)
        const int r1 = rr;
        const int gate = wv >> 2, usub = wv & 3;
        const int colw = gate*HH + 64*r1 + 16*usub;
        short8 wf[8];
        {
            const int col = colw + (l & 15);
            const int kb = (l >> 4) << 3;
            #pragma unroll
            for (int kk = 0; kk < 8; ++kk){
                short8 s;
                #pragma unroll
                for (int j = 0; j < 8; ++j)
                    s[j] = (short)f2bf(W1[(size_t)(HH + kk*32 + kb + j)*GG + col]);
                wf[kk] = s;
            }
        }
        u16*  hA = (u16*)smem;               // [2][256] bf16
        float* gm = (float*)(smem + 1024);   // [4][64][2] f32
        float creg = 0.f;
        const int au = tid >> 1, ab = tid & 1;

        for (int t = 0; t < TT; ++t){
            float c0 = 0.f, c1 = 0.f;
            if (l < 16){
                c0 = G1t[((size_t)t*BB + 2*g + 0)*GG + colw + l];
                c1 = G1t[((size_t)t*BB + 2*g + 1)*GG + colw + l];
            }
            f32x4 acc = {c0, c1, 0.f, 0.f};
            if (t > 0){
                poll_ge(&myA[t-1], 4);
                if (tid < 512){
                    int b = tid >> 8, u = tid & 255;
                    float hv = ld_coh(&h1x[((size_t)(t-1)*BB + 2*g + b)*HH + u]);
                    hA[b*256 + u] = f2bf(hv);
                }
                __syncthreads();
                const u16* ap = hA + (l & 1)*256 + ((l >> 4) << 3);
                #pragma unroll
                for (int kk = 0; kk < 8; ++kk)
                    acc = __builtin_amdgcn_mfma_f32_16x16x32_bf16(
                            *(const short8*)(ap + kk*32), wf[kk], acc, 0, 0, 0);
            }
            if (l < 16){
                gm[(gate*64 + usub*16 + l)*2 + 0] = acc[0];
                gm[(gate*64 + usub*16 + l)*2 + 1] = acc[1];
            }
            __syncthreads();
            if (tid < 128){
                float gi_ = gm[(0*64 + au)*2 + ab];
                float gj_ = gm[(1*64 + au)*2 + ab];
                float gf_ = gm[(2*64 + au)*2 + ab];
                float go_ = gm[(3*64 + au)*2 + ab];
                float cn = creg * sigm(gf_ + 1.0f) + sigm(gi_)*tanha(gj_);
                float hn = tanha(cn)*sigm(go_);
                creg = cn;
                st_coh(&h1x[((size_t)t*BB + 2*g + ab)*HH + 64*r1 + au], hn);
            }
            __syncthreads();   // drains vmcnt of all waves before flag
            if (tid == 0)
                __hip_atomic_fetch_add(&myA[t], 1, __ATOMIC_RELAXED, __HIP_MEMORY_SCOPE_AGENT);
        }
    } else {
        // ========== L2: gates[2, 128cols] = b2 + [h1_t ; h2_{t-1}] @ W2   (block owns units 32*r2..+32)
        const int r2 = rr - 4;
        const int nt = wv >> 1, kh = wv & 1;
        const int gate = nt >> 1, usub = nt & 1;
        const int colw = gate*HH + 32*r2 + 16*usub;
        short8 wf[8];
        {
            const int col = colw + (l & 15);
            const int kb = (l >> 4) << 3;
            #pragma unroll
            for (int kk = 0; kk < 8; ++kk){
                short8 s;
                #pragma unroll
                for (int j = 0; j < 8; ++j)
                    s[j] = (short)f2bf(W2[(size_t)(kh*256 + kk*32 + kb + j)*GG + col]);
                wf[kk] = s;
            }
        }
        u16*  uB = (u16*)smem;               // [2][512] bf16
        float* gm = (float*)(smem + 2048);   // [4][32][2][2] f32
        float creg = 0.f;
        const int au = tid >> 1, ab = tid & 1;
        float bv0 = 0.f, bv1 = 0.f, bv2 = 0.f, bv3 = 0.f;
        if (tid < 64){
            bv0 = b2[0*HH + 32*r2 + au];
            bv1 = b2[1*HH + 32*r2 + au];
            bv2 = b2[2*HH + 32*r2 + au];
            bv3 = b2[3*HH + 32*r2 + au];
        }

        for (int it = 1; it <= TT; ++it){
            const int tt = it - 1;
            poll_ge(&myA[tt], 4);
            if (tt > 0) poll_ge(&myB[tt-1], 8);
            {
                int z = tid >> 9, b = (tid >> 8) & 1, u = tid & 255;
                float v = 0.f;
                if (z == 0)           v = ld_coh(&h1x[((size_t)tt*BB + 2*g + b)*HH + u]);
                else if (tt > 0)      v = ld_coh(&h2x[((size_t)(tt-1)*BB + 2*g + b)*HH + u]);
                uB[b*512 + z*256 + u] = f2bf(v);
            }
            __syncthreads();
            f32x4 acc = {0.f, 0.f, 0.f, 0.f};
            const u16* ap = uB + (l & 1)*512 + kh*256 + ((l >> 4) << 3);
            #pragma unroll
            for (int kk = 0; kk < 8; ++kk)
                acc = __builtin_amdgcn_mfma_f32_16x16x32_bf16(
                        *(const short8*)(ap + kk*32), wf[kk], acc, 0, 0, 0);
            if (l < 16){
                gm[((gate*32 + usub*16 + l)*2 + 0)*2 + kh] = acc[0];
                gm[((gate*32 + usub*16 + l)*2 + 1)*2 + kh] = acc[1];
            }
            __syncthreads();
            if (tid < 64){
                float gi_ = gm[((0*32 + au)*2 + ab)*2 + 0] + gm[((0*32 + au)*2 + ab)*2 + 1] + bv0;
                float gj_ = gm[((1*32 + au)*2 + ab)*2 + 0] + gm[((1*32 + au)*2 + ab)*2 + 1] + bv1;
                float gf_ = gm[((2*32 + au)*2 + ab)*2 + 0] + gm[((2*32 + au)*2 + ab)*2 + 1] + bv2;
                float go_ = gm[((3*32 + au)*2 + ab)*2 + 0] + gm[((3*32 + au)*2 + ab)*2 + 1] + bv3;
                float cn = creg * sigm(gf_ + 1.0f) + sigm(gi_)*tanha(gj_);
                float hn = tanha(cn)*sigm(go_);
                creg = cn;
                st_coh(&h2x[((size_t)tt*BB + 2*g + ab)*HH + 32*r2 + au], hn);
                h2b[((size_t)(2*g + ab)*TT + tt)*HH + 32*r2 + au] = f2bf(hn);
            }
            __syncthreads();   // drains vmcnt before flag
            if (tid == 0)
                __hip_atomic_fetch_add(&myB[tt], 1, __ATOMIC_RELAXED, __HIP_MEMORY_SCOPE_AGENT);
        }
    }
}

// ---------------- out = h2b[4096,256] @ WoutT^T + bout  (128x128 tile, gload_lds dbuf, swizzled LDS)
__global__ __launch_bounds__(256) void out_gemm(const u16* __restrict__ A, const u16* __restrict__ Bt,
                                                const float* __restrict__ bout, float* __restrict__ out){
    __shared__ __align__(16) u16 lds[2][2][8192];   // [buf][A/B][128 rows x 64 k] bf16, XOR-swizzled
    const int bid = blockIdx.x;
    const int wg  = (bid & 7)*1572 + (bid >> 3);    // bijective XCD swizzle (12576 = 8*1572)
    const int mb = wg & 31, nb = wg >> 5;           // n-major: 32 consecutive wg share B tile
    const int m0 = mb*128, n0 = nb*128;
    const int tid = threadIdx.x;
    const int l = tid & 63;
    const int wv = tid >> 6;
    const int wm = wv >> 1, wn = wv & 1;
    const int lr = l & 15, lh = l >> 4;

    f32x4 acc[4][4];
    #pragma unroll
    for (int mf = 0; mf < 4; ++mf)
        #pragma unroll
        for (int nf = 0; nf < 4; ++nf) acc[mf][nf] = (f32x4){0.f,0.f,0.f,0.f};

    // stage K-slab k0 into buffer c: linear LDS dest, inverse-swizzled global source (rule #21)
    #define STAGE(c, k0) { \
        _Pragma("unroll") \
        for (int j = 0; j < 4; ++j){ \
            int f = j*256 + tid; \
            int row = f >> 3; \
            int kps = (f & 7) ^ (row & 7); \
            gl_lds16(A  + (size_t)(m0+row)*256 + (k0) + kps*8, (char*)&lds[c][0][0] + f*16); \
            gl_lds16(Bt + (size_t)(n0+row)*256 + (k0) + kps*8, (char*)&lds[c][1][0] + f*16); \
        } }

    STAGE(0, 0)
    __syncthreads();
    #pragma unroll
    for (int ks = 0; ks < 4; ++ks){
        const int cur = ks & 1;
        if (ks < 3) STAGE(cur^1, (ks+1)*64)
        const char* ab = (const char*)&lds[cur][0][0];
        const char* bbp = (const char*)&lds[cur][1][0];
        #pragma unroll
        for (int ksub = 0; ksub < 2; ++ksub){
            short8 af[4], bf[4];
            const int kp = ksub*4 + lh;
            #pragma unroll
            for (int mf = 0; mf < 4; ++mf){
                int row = wm*64 + mf*16 + lr;
                af[mf] = *(const short8*)(ab + row*128 + ((kp ^ (row&7)) << 4));
            }
            #pragma unroll
            for (int nf = 0; nf < 4; ++nf){
                int row = wn*64 + nf*16 + lr;
                bf[nf] = *(const short8*)(bbp + row*128 + ((kp ^ (row&7)) << 4));
            }
            #pragma unroll
            for (int mf = 0; mf < 4; ++mf)
                #pragma unroll
                for (int nf = 0; nf < 4; ++nf)
                    acc[mf][nf] = __builtin_amdgcn_mfma_f32_16x16x32_bf16(af[mf], bf[nf], acc[mf][nf], 0, 0, 0);
        }
        __syncthreads();
    }
    #undef STAGE

    // epilogue: acc + bias -> LDS f32 tile (reuse staging LDS), then coalesced float4 stores
    float* ldsF = (float*)&lds[0][0][0];   // 128 x 128 f32 = 64 KB
    #pragma unroll
    for (int nf = 0; nf < 4; ++nf){
        int col = wn*64 + nf*16 + lr;
        int gcol = n0 + col;
        float bb2 = (gcol < VV) ? bout[gcol] : 0.0f;
        #pragma unroll
        for (int mf = 0; mf < 4; ++mf)
            #pragma unroll
            for (int r = 0; r < 4; ++r){
                int row = wm*64 + mf*16 + lh*4 + r;
                ldsF[row*128 + col] = acc[mf][nf][r] + bb2;
            }
    }
    __syncthreads();
    #pragma unroll
    for (int j = 0; j < 16; ++j){
        int f = j*256 + tid;         // 16B unit
        int row = f >> 5;
        int c4 = (f & 31)*4;
        int gcol = n0 + c4;
        float4 v = *(const float4*)(ldsF + row*128 + c4);
        if (gcol + 3 < VV){
            *(float4*)(&out[(size_t)(m0+row)*VV + gcol]) = v;
        } else {
            #pragma unroll
            for (int e = 0; e < 4; ++e)
                if (gcol + e < VV) out[(size_t)(m0+row)*VV + gcol + e] = ((const float*)&v)[e];
        }
    }
}

extern "C" void kernel_launch(void* const* d_in, const int* in_sizes, int n_in,
                              void* d_out, int out_size, void* d_ws, size_t ws_size,
                              hipStream_t stream) {
    const int*   tok  = (const int*)d_in[0];
    const float* emb  = (const float*)d_in[1];
    const float* W1   = (const float*)d_in[2];
    const float* b1   = (const float*)d_in[3];
    const float* W2   = (const float*)d_in[4];
    const float* b2   = (const float*)d_in[5];
    const float* Wout = (const float*)d_in[6];
    const float* bout = (const float*)d_in[7];
    float* out = (float*)d_out;
    char* ws = (char*)d_ws;

    int*   ctrA  = (int*)(ws);                          //  8,192 B  [8][256]
    int*   ctrB  = (int*)(ws + 8192);                   //  8,192 B  [8][256]
    float* G1t   = (float*)(ws + 32768);                // 16,777,216 B  [T*16][1024]
    float* h1x   = (float*)(ws + 32768 + 16777216);     //  4,194,304 B  [T][16][256]
    float* h2x   = (float*)(ws + 32768 + 20971520);     //  4,194,304 B  [T][16][256]
    u16*   h2b   = (u16*)  (ws + 32768 + 25165824);     //  2,097,152 B  [16][T][256]
    u16*   WoutT = (u16*)  (ws + 32768 + 27262976);     // 25,755,648 B  [50304][256]

    hipMemsetAsync(ws, 0, 32768, stream);   // zero step counters (replay-safe)
    g1_kernel<<<dim3(64, 16), 256, 0, stream>>>(tok, emb, W1, b1, G1t);
    persist_kernel<<<224, 1024, 0, stream>>>(G1t, W1, W2, b2, Wout, WoutT,
                                             h1x, h2x, h2b, ctrA, ctrB);
    out_gemm<<<12576, 256, 0, stream>>>(h2b, WoutT, bout, out);
}

// Round 5
// 883.809 us; speedup vs baseline: 3.7372x; 1.2609x over previous
//
#include <hip/hip_runtime.h>
#include <hip/hip_bf16.h>
#include <stdint.h>

#define BB 16
#define TT 256
#define HH 256
#define EE 256
#define GG 1024      // 4*H
#define VV 50257
#define NN 4096      // B*T

typedef unsigned short u16;
typedef __attribute__((ext_vector_type(8))) short short8;
typedef __attribute__((ext_vector_type(4))) float f32x4;

__device__ __forceinline__ float sigm(float x){
    float e = __builtin_amdgcn_exp2f(fminf(-x*1.44269504f, 60.0f));
    return 1.0f/(1.0f+e);
}
__device__ __forceinline__ float tanha(float x){
    float e = __builtin_amdgcn_exp2f(fminf(x*2.885390082f, 60.0f));
    return (e-1.0f)/(e+1.0f);
}
__device__ __forceinline__ u16 f2bf(float f){
    uint32_t u = __float_as_uint(f);
    u = (u + 0x7FFFu + ((u>>16)&1u)) >> 16;
    return (u16)u;
}
// agent-scope (device-coherent) ops; data-as-flag polling. Sentinel bf16 = 0xFFFF (NaN, never produced).
__device__ __forceinline__ void st16_coh(u16* p, u16 v){
    __hip_atomic_store(p, v, __ATOMIC_RELAXED, __HIP_MEMORY_SCOPE_AGENT);
}
__device__ __forceinline__ uint32_t poll_pair(const uint32_t* p){
    uint32_t v = __hip_atomic_load(p, __ATOMIC_RELAXED, __HIP_MEMORY_SCOPE_AGENT);
    while ((v & 0xFFFFu) == 0xFFFFu || (v >> 16) == 0xFFFFu){
        __builtin_amdgcn_s_sleep(1);
        v = __hip_atomic_load(p, __ATOMIC_RELAXED, __HIP_MEMORY_SCOPE_AGENT);
    }
    return v;
}
__device__ __forceinline__ void gl_lds16(const void* g, void* s){
    __builtin_amdgcn_global_load_lds((const __attribute__((address_space(1))) unsigned int*)g,
                                     (__attribute__((address_space(3))) unsigned int*)s, 16, 0, 0);
}

// ---------------- G1t[(t*16+b)][g] = b1[g] + sum_e emb[tok[b*T+t]][e] * W1[e][g]
__global__ __launch_bounds__(256) void g1_kernel(const int* __restrict__ tok, const float* __restrict__ emb,
                                                 const float* __restrict__ W1, const float* __restrict__ b1,
                                                 float* __restrict__ G1t){
    __shared__ float xs[64*64];
    __shared__ float wsm[64*64];
    int n0 = blockIdx.x * 64;
    int g0 = blockIdx.y * 64;
    int tid = threadIdx.x;
    int sl = tid & 63;
    int kk = (tid >> 6) * 16;
    int mytok = tok[n0 + sl];
    float acc[4][4] = {};
    int ni = tid & 15, gi = tid >> 4;
    for (int kc = 0; kc < 4; ++kc){
        int k0 = kc*64;
        __syncthreads();
        #pragma unroll
        for (int i4 = 0; i4 < 4; ++i4){
            float4 xv = *(const float4*)(&emb[(size_t)mytok*EE + k0 + kk + i4*4]);
            xs[(kk+i4*4+0)*64 + sl] = xv.x;
            xs[(kk+i4*4+1)*64 + sl] = xv.y;
            xs[(kk+i4*4+2)*64 + sl] = xv.z;
            xs[(kk+i4*4+3)*64 + sl] = xv.w;
        }
        #pragma unroll
        for (int i = 0; i < 16; ++i){
            wsm[(kk+i)*64 + sl] = W1[(size_t)(k0+kk+i)*GG + g0 + sl];
        }
        __syncthreads();
        for (int k = 0; k < 64; ++k){
            float4 av = *(const float4*)(&xs[k*64 + ni*4]);
            float4 bv = *(const float4*)(&wsm[k*64 + gi*4]);
            float a_[4] = {av.x, av.y, av.z, av.w};
            float b_[4] = {bv.x, bv.y, bv.z, bv.w};
            #pragma unroll
            for (int i = 0; i < 4; ++i)
                #pragma unroll
                for (int j = 0; j < 4; ++j)
                    acc[i][j] += a_[i]*b_[j];
        }
    }
    #pragma unroll
    for (int i = 0; i < 4; ++i){
        int n = n0 + ni*4 + i;
        int b = n >> 8;
        int tt_ = n & 255;
        float4 o;
        o.x = acc[i][0] + b1[g0+gi*4+0];
        o.y = acc[i][1] + b1[g0+gi*4+1];
        o.z = acc[i][2] + b1[g0+gi*4+2];
        o.w = acc[i][3] + b1[g0+gi*4+3];
        *(float4*)(&G1t[(size_t)(tt_*16 + b)*GG + g0 + gi*4]) = o;
    }
}

// ---------------- persistent: 96 recurrence blocks (8 groups x (4 L1 + 8 L2)), 128 transpose workers
// h1y: [T][8grp][2b][256u] bf16 exchange buffer (sentinel 0xFFFF)
// h2b: [16b][T][256u] bf16 — BOTH the L2 exchange buffer and out_gemm's A matrix
__global__ __launch_bounds__(1024) void persist_kernel(
        const float* __restrict__ G1t, const float* __restrict__ W1,
        const float* __restrict__ W2, const float* __restrict__ b2,
        const float* __restrict__ Wout, u16* __restrict__ WoutT,
        u16* __restrict__ h1y, u16* __restrict__ h2b){
    __shared__ __align__(16) char smem[12288];
    const int bid = blockIdx.x;
    const int tid = threadIdx.x;

    if (bid >= 96){
        // ---- Wout cast+transpose workers: Wout[256][50257] f32 -> WoutT[50304][256] bf16
        u16* tile = (u16*)smem;   // [64][66]
        const int r = tid >> 4, i = tid & 15;
        for (int tau = bid - 96; tau < 786*4; tau += 128){
            int ky = tau / 786;
            int nx = tau - ky*786;
            int n0 = nx*64, k0 = ky*64;
            #pragma unroll
            for (int jj = 0; jj < 4; ++jj){
                int n = n0 + i*4 + jj;
                float f = (n < VV) ? Wout[(size_t)(k0 + r)*VV + n] : 0.0f;
                tile[(i*4 + jj)*66 + r] = f2bf(f);
            }
            __syncthreads();
            {
                int kl = i*4;
                uint2 v;
                v.x = (uint32_t)tile[r*66 + kl+0] | ((uint32_t)tile[r*66 + kl+1] << 16);
                v.y = (uint32_t)tile[r*66 + kl+2] | ((uint32_t)tile[r*66 + kl+3] << 16);
                *(uint2*)(&WoutT[(size_t)(n0 + r)*256 + k0 + kl]) = v;
            }
            __syncthreads();
        }
        return;
    }

    const int g  = bid & 7;    // group (2 batches: 2g, 2g+1); blocks of a group share bid%8
    const int rr = bid >> 3;   // 0..3 = L1 slice, 4..11 = L2 slice
    const int l  = tid & 63;
    const int wv = tid >> 6;
    uint32_t* h1y32 = (uint32_t*)h1y;
    uint32_t* h2b32 = (uint32_t*)h2b;

    if (rr < 4){
        // ========== L1: gates[2, 256cols] = G1t + h1_{t-1} @ W1rec   (block owns units 64*r1..+64)
        const int r1 = rr;
        const int gate = wv >> 2, usub = wv & 3;
        const int colw = gate*HH + 64*r1 + 16*usub;
        short8 wf[8];
        {
            const int col = colw + (l & 15);
            const int kb = (l >> 4) << 3;
            #pragma unroll
            for (int kk = 0; kk < 8; ++kk){
                short8 s;
                #pragma unroll
                for (int j = 0; j < 8; ++j)
                    s[j] = (short)f2bf(W1[(size_t)(HH + kk*32 + kb + j)*GG + col]);
                wf[kk] = s;
            }
        }
        u16*      hA   = (u16*)smem;             // [2][256] bf16
        uint32_t* hA32 = (uint32_t*)smem;
        float* gm = (float*)(smem + 1024);       // [4][64][2] f32
        float creg = 0.f;
        const int au = tid >> 1, ab = tid & 1;   // activation lane mapping (tid<128)

        for (int t = 0; t < TT; ++t){
            // issue G1t loads first — latency hides under the poll
            float c0 = 0.f, c1 = 0.f;
            if (l < 16){
                c0 = G1t[((size_t)t*BB + 2*g + 0)*GG + colw + l];
                c1 = G1t[((size_t)t*BB + 2*g + 1)*GG + colw + l];
            }
            f32x4 acc = {c0, c1, 0.f, 0.f};
            if (t > 0){
                if (tid < 256){
                    int b = tid >> 7, p = tid & 127;   // pair index: units 2p,2p+1
                    hA32[b*128 + p] = poll_pair(&h1y32[(((size_t)(t-1)*8 + g)*2 + b)*128 + p]);
                }
                __syncthreads();
                const u16* ap = hA + (l & 1)*256 + ((l >> 4) << 3);
                #pragma unroll
                for (int kk = 0; kk < 8; ++kk)
                    acc = __builtin_amdgcn_mfma_f32_16x16x32_bf16(
                            *(const short8*)(ap + kk*32), wf[kk], acc, 0, 0, 0);
            }
            if (l < 16){
                gm[(gate*64 + usub*16 + l)*2 + 0] = acc[0];
                gm[(gate*64 + usub*16 + l)*2 + 1] = acc[1];
            }
            __syncthreads();
            if (tid < 128){
                float gi_ = gm[(0*64 + au)*2 + ab];
                float gj_ = gm[(1*64 + au)*2 + ab];
                float gf_ = gm[(2*64 + au)*2 + ab];
                float go_ = gm[(3*64 + au)*2 + ab];
                float cn = creg * sigm(gf_ + 1.0f) + sigm(gi_)*tanha(gj_);
                float hn = tanha(cn)*sigm(go_);
                creg = cn;
                // store = signal (data-as-flag); no barrier, no flag
                st16_coh(&h1y[(((size_t)t*8 + g)*2 + ab)*256 + 64*r1 + au], f2bf(hn));
            }
            __syncthreads();   // protect gm/hA reuse across iterations
        }
    } else {
        // ========== L2: gates[2, 128cols] = b2 + [h1_t ; h2_{t-1}] @ W2   (block owns units 32*r2..+32)
        const int r2 = rr - 4;
        const int nt = wv >> 1, kh = wv & 1;
        const int gate = nt >> 1, usub = nt & 1;
        const int colw = gate*HH + 32*r2 + 16*usub;
        short8 wf[8];
        {
            const int col = colw + (l & 15);
            const int kb = (l >> 4) << 3;
            #pragma unroll
            for (int kk = 0; kk < 8; ++kk){
                short8 s;
                #pragma unroll
                for (int j = 0; j < 8; ++j)
                    s[j] = (short)f2bf(W2[(size_t)(kh*256 + kk*32 + kb + j)*GG + col]);
                wf[kk] = s;
            }
        }
        u16*      uB   = (u16*)smem;             // [2][512] bf16: [b][h1(256);h2(256)]
        uint32_t* uB32 = (uint32_t*)smem;
        float* gm = (float*)(smem + 2048);       // [4][32][2][2] f32
        float creg = 0.f;
        const int au = tid >> 1, ab = tid & 1;
        float bv0 = 0.f, bv1 = 0.f, bv2 = 0.f, bv3 = 0.f;
        if (tid < 64){
            bv0 = b2[0*HH + 32*r2 + au];
            bv1 = b2[1*HH + 32*r2 + au];
            bv2 = b2[2*HH + 32*r2 + au];
            bv3 = b2[3*HH + 32*r2 + au];
        }

        for (int tt = 0; tt < TT; ++tt){
            if (tid < 512){
                int b = tid >> 8, q = tid & 255;   // q<128: h1 pair q; q>=128: h2 pair q-128
                uint32_t v;
                if (q < 128)
                    v = poll_pair(&h1y32[(((size_t)tt*8 + g)*2 + b)*128 + q]);
                else if (tt > 0)
                    v = poll_pair(&h2b32[((size_t)(2*g + b)*TT + (tt-1))*128 + (q - 128)]);
                else
                    v = 0;
                uB32[b*256 + q] = v;
            }
            __syncthreads();
            f32x4 acc = {0.f, 0.f, 0.f, 0.f};
            const u16* ap = uB + (l & 1)*512 + kh*256 + ((l >> 4) << 3);
            #pragma unroll
            for (int kk = 0; kk < 8; ++kk)
                acc = __builtin_amdgcn_mfma_f32_16x16x32_bf16(
                        *(const short8*)(ap + kk*32), wf[kk], acc, 0, 0, 0);
            if (l < 16){
                gm[((gate*32 + usub*16 + l)*2 + 0)*2 + kh] = acc[0];
                gm[((gate*32 + usub*16 + l)*2 + 1)*2 + kh] = acc[1];
            }
            __syncthreads();
            if (tid < 64){
                float gi_ = gm[((0*32 + au)*2 + ab)*2 + 0] + gm[((0*32 + au)*2 + ab)*2 + 1] + bv0;
                float gj_ = gm[((1*32 + au)*2 + ab)*2 + 0] + gm[((1*32 + au)*2 + ab)*2 + 1] + bv1;
                float gf_ = gm[((2*32 + au)*2 + ab)*2 + 0] + gm[((2*32 + au)*2 + ab)*2 + 1] + bv2;
                float go_ = gm[((3*32 + au)*2 + ab)*2 + 0] + gm[((3*32 + au)*2 + ab)*2 + 1] + bv3;
                float cn = creg * sigm(gf_ + 1.0f) + sigm(gi_)*tanha(gj_);
                float hn = tanha(cn)*sigm(go_);
                creg = cn;
                // store = signal; h2b doubles as out_gemm's A matrix
                st16_coh(&h2b[((size_t)(2*g + ab)*TT + tt)*HH + 32*r2 + au], f2bf(hn));
            }
            __syncthreads();   // protect gm/uB reuse across iterations
        }
    }
}

// ---------------- out = h2b[4096,256] @ WoutT^T + bout  (128x128 tile, gload_lds dbuf, swizzled LDS)
__global__ __launch_bounds__(256) void out_gemm(const u16* __restrict__ A, const u16* __restrict__ Bt,
                                                const float* __restrict__ bout, float* __restrict__ out){
    __shared__ __align__(16) u16 lds[2][2][8192];   // [buf][A/B][128 rows x 64 k] bf16, XOR-swizzled
    const int bid = blockIdx.x;
    const int wg  = (bid & 7)*1572 + (bid >> 3);    // bijective XCD swizzle (12576 = 8*1572)
    const int mb = wg & 31, nb = wg >> 5;           // n-major: 32 consecutive wg share B tile
    const int m0 = mb*128, n0 = nb*128;
    const int tid = threadIdx.x;
    const int l = tid & 63;
    const int wv = tid >> 6;
    const int wm = wv >> 1, wn = wv & 1;
    const int lr = l & 15, lh = l >> 4;

    f32x4 acc[4][4];
    #pragma unroll
    for (int mf = 0; mf < 4; ++mf)
        #pragma unroll
        for (int nf = 0; nf < 4; ++nf) acc[mf][nf] = (f32x4){0.f,0.f,0.f,0.f};

    #define STAGE(c, k0) { \
        _Pragma("unroll") \
        for (int j = 0; j < 4; ++j){ \
            int f = j*256 + tid; \
            int row = f >> 3; \
            int kps = (f & 7) ^ (row & 7); \
            gl_lds16(A  + (size_t)(m0+row)*256 + (k0) + kps*8, (char*)&lds[c][0][0] + f*16); \
            gl_lds16(Bt + (size_t)(n0+row)*256 + (k0) + kps*8, (char*)&lds[c][1][0] + f*16); \
        } }

    STAGE(0, 0)
    __syncthreads();
    #pragma unroll
    for (int ks = 0; ks < 4; ++ks){
        const int cur = ks & 1;
        if (ks < 3) STAGE(cur^1, (ks+1)*64)
        const char* ab = (const char*)&lds[cur][0][0];
        const char* bbp = (const char*)&lds[cur][1][0];
        #pragma unroll
        for (int ksub = 0; ksub < 2; ++ksub){
            short8 af[4], bf[4];
            const int kp = ksub*4 + lh;
            #pragma unroll
            for (int mf = 0; mf < 4; ++mf){
                int row = wm*64 + mf*16 + lr;
                af[mf] = *(const short8*)(ab + row*128 + ((kp ^ (row&7)) << 4));
            }
            #pragma unroll
            for (int nf = 0; nf < 4; ++nf){
                int row = wn*64 + nf*16 + lr;
                bf[nf] = *(const short8*)(bbp + row*128 + ((kp ^ (row&7)) << 4));
            }
            #pragma unroll
            for (int mf = 0; mf < 4; ++mf)
                #pragma unroll
                for (int nf = 0; nf < 4; ++nf)
                    acc[mf][nf] = __builtin_amdgcn_mfma_f32_16x16x32_bf16(af[mf], bf[nf], acc[mf][nf], 0, 0, 0);
        }
        __syncthreads();
    }
    #undef STAGE

    // epilogue: acc + bias -> LDS f32 tile, then coalesced float4 stores
    float* ldsF = (float*)&lds[0][0][0];   // 128 x 128 f32 = 64 KB
    #pragma unroll
    for (int nf = 0; nf < 4; ++nf){
        int col = wn*64 + nf*16 + lr;
        int gcol = n0 + col;
        float bb2 = (gcol < VV) ? bout[gcol] : 0.0f;
        #pragma unroll
        for (int mf = 0; mf < 4; ++mf)
            #pragma unroll
            for (int r = 0; r < 4; ++r){
                int row = wm*64 + mf*16 + lh*4 + r;
                ldsF[row*128 + col] = acc[mf][nf][r] + bb2;
            }
    }
    __syncthreads();
    #pragma unroll
    for (int j = 0; j < 16; ++j){
        int f = j*256 + tid;
        int row = f >> 5;
        int c4 = (f & 31)*4;
        int gcol = n0 + c4;
        float4 v = *(const float4*)(ldsF + row*128 + c4);
        if (gcol + 3 < VV){
            *(float4*)(&out[(size_t)(m0+row)*VV + gcol]) = v;
        } else {
            #pragma unroll
            for (int e = 0; e < 4; ++e)
                if (gcol + e < VV) out[(size_t)(m0+row)*VV + gcol + e] = ((const float*)&v)[e];
        }
    }
}

extern "C" void kernel_launch(void* const* d_in, const int* in_sizes, int n_in,
                              void* d_out, int out_size, void* d_ws, size_t ws_size,
                              hipStream_t stream) {
    const int*   tok  = (const int*)d_in[0];
    const float* emb  = (const float*)d_in[1];
    const float* W1   = (const float*)d_in[2];
    const float* b1   = (const float*)d_in[3];
    const float* W2   = (const float*)d_in[4];
    const float* b2   = (const float*)d_in[5];
    const float* Wout = (const float*)d_in[6];
    const float* bout = (const float*)d_in[7];
    float* out = (float*)d_out;
    char* ws = (char*)d_ws;

    u16*   h1y   = (u16*)  (ws);                        //  2,097,152 B  [T][8][2][256] bf16
    u16*   h2b   = (u16*)  (ws + 2097152);              //  2,097,152 B  [16][T][256] bf16
    float* G1t   = (float*)(ws + 4194304);              // 16,777,216 B  [T*16][1024]
    u16*   WoutT = (u16*)  (ws + 4194304 + 16777216);   // 25,755,648 B  [50304][256]

    hipMemsetAsync(ws, 0xFF, 4194304, stream);   // sentinel-fill h1y + h2b (replay-safe)
    g1_kernel<<<dim3(64, 16), 256, 0, stream>>>(tok, emb, W1, b1, G1t);
    persist_kernel<<<224, 1024, 0, stream>>>(G1t, W1, W2, b2, Wout, WoutT, h1y, h2b);
    out_gemm<<<12576, 256, 0, stream>>>(h2b, WoutT, bout, out);
}